// Round 6
// baseline (327.839 us; speedup 1.0000x reference)
//
#include <hip/hip_runtime.h>
#include <hip/hip_cooperative_groups.h>
#include <math.h>

namespace cg = cooperative_groups;

#define NN 8192
#define PP 32
#define HH 512
#define KK 100
#define DD 64
#define RR 32
#define MM 96            // C cols: 32 gate + 64 w
#define SB 32            // steps per segment
#define NSEG 256         // segments == blocks

// workspace layout (float offsets)
#define OFF_VINV 0            // 64*64
#define OFF_EAT  4096         // 100*64 (E@alpha)^T
#define OFF_RHT  10496        // 100*64 (Vinv@E@alpha)^T
#define OFF_Y0   16896        // 64
#define OFF_BAGG 16960        // 256*32*4 segment aggregates
#define OFF_C    49728        // 8192*96 gemm out
#define OFF_COEF 836160       // 8192*32*4 step coefficients

// LDS layout (floats). Phase-local; phases separated by barriers.
//  P0 block0 Newton: Vt@0, X@4096, Xt@8192, T@12288
//  P0 GEMM: uT@0 (2048), mT@2048 (6144)
//  P1: vinvT@0 (64*68), ct@4352 (32*96), ag@7424 (f4[16][32])
//  P2: vt@0 (64*68), ag@4352, pref@6400, yl@8448 (32*68), yb@10624
#define L1_CT   4352
#define L1_AG   7424
#define L2_AG   4352
#define L2_PREF 6400
#define L2_YL   8448
#define L2_YB   10624

__device__ __forceinline__ float sp_fast(float x) {   // softplus
    return x > 15.f ? x : __logf(1.f + __expf(x));
}
__device__ __forceinline__ float rcp_fast(float x) {
    float r;
    asm("v_rcp_f32 %0, %1" : "=v"(r) : "v"(x));
    return r;
}
__device__ __forceinline__ float4 comp_aff(float4 f, float4 g) {  // f after g
    float4 r;
    r.x = f.x * g.x - f.y * g.y;
    r.y = f.x * g.y + f.y * g.x;
    r.z = f.x * g.z - f.y * g.w + f.z;
    r.w = f.x * g.w + f.y * g.z + f.w;
    return r;
}

#define IDX(r,c) ((r)*64 + ((c) ^ (((r)&7)<<2)))

__global__ void __launch_bounds__(512) mega(
    const float* __restrict__ times, const int* __restrict__ marks,
    const float* __restrict__ u, const float* __restrict__ llr,
    const float* __restrict__ lim, const float* __restrict__ V,
    const float* __restrict__ B, const float* __restrict__ E,
    const float* __restrict__ alpha, const float* __restrict__ gate_w,
    const float* __restrict__ gate_b, const float* __restrict__ x0,
    float* __restrict__ ws, float* __restrict__ out, int phase) {
    __shared__ float sm[16384];
    cg::grid_group grid = cg::this_grid();
    const int b = blockIdx.x, t = threadIdx.x;

    // ================= P0: (block 0: Newton inverse + EAT/RHT/y0), GEMM =====
    if (phase & 1) {
        if (b == 0) {
            float* Vt = sm;            // Vt[k][i] = V[i][k] (swizzled)
            float* X  = sm + 4096;
            float* Xt = sm + 8192;     // Xt[k][i] = X[i][k]
            float* T  = sm + 12288;
            const int i0 = ((t & 255) >> 4) << 2;
            const int j0 = (t & 15) << 2;
            float nx[4][4];
            if (t < 256) {
                #pragma unroll
                for (int r = 0; r < 4; r++) {
                    float4 v4 = *(const float4*)&V[(i0 + r) * DD + j0];
                    float vv[4] = {v4.x, v4.y, v4.z, v4.w};
                    #pragma unroll
                    for (int s = 0; s < 4; s++) {
                        Vt[IDX(j0 + s, i0 + r)] = vv[s];
                        float xv = ((i0 + r) == (j0 + s) ? 2.f : 0.f) - vv[s];
                        nx[r][s] = xv;
                        Xt[IDX(j0 + s, i0 + r)] = xv;
                    }
                    *(float4*)&X[IDX(i0 + r, j0)] =
                        make_float4(nx[r][0], nx[r][1], nx[r][2], nx[r][3]);
                }
            }
            __syncthreads();
            for (int it = 0; it < 3; it++) {
                float ac[4][4];
                if (t < 256) {
                    #pragma unroll
                    for (int r = 0; r < 4; r++)
                        #pragma unroll
                        for (int s = 0; s < 4; s++) ac[r][s] = 0.f;
                    for (int k = 0; k < DD; k++) {          // T = V @ X
                        float4 a4 = *(float4*)&Vt[IDX(k, i0)];
                        float4 b4 = *(float4*)&X[IDX(k, j0)];
                        float av[4] = {a4.x, a4.y, a4.z, a4.w};
                        float bv[4] = {b4.x, b4.y, b4.z, b4.w};
                        #pragma unroll
                        for (int r = 0; r < 4; r++)
                            #pragma unroll
                            for (int s = 0; s < 4; s++)
                                ac[r][s] = fmaf(av[r], bv[s], ac[r][s]);
                    }
                    #pragma unroll
                    for (int r = 0; r < 4; r++)
                        *(float4*)&T[IDX(i0 + r, j0)] =
                            make_float4(ac[r][0], ac[r][1], ac[r][2], ac[r][3]);
                }
                __syncthreads();
                if (t < 256) {
                    #pragma unroll
                    for (int r = 0; r < 4; r++)
                        #pragma unroll
                        for (int s = 0; s < 4; s++) ac[r][s] = 0.f;
                    for (int k = 0; k < DD; k++) {          // X @ T
                        float4 a4 = *(float4*)&Xt[IDX(k, i0)];
                        float4 b4 = *(float4*)&T[IDX(k, j0)];
                        float av[4] = {a4.x, a4.y, a4.z, a4.w};
                        float bv[4] = {b4.x, b4.y, b4.z, b4.w};
                        #pragma unroll
                        for (int r = 0; r < 4; r++)
                            #pragma unroll
                            for (int s = 0; s < 4; s++)
                                ac[r][s] = fmaf(av[r], bv[s], ac[r][s]);
                    }
                    #pragma unroll
                    for (int r = 0; r < 4; r++) {
                        float4 xo = *(float4*)&X[IDX(i0 + r, j0)];
                        nx[r][0] = 2.f * xo.x - ac[r][0];
                        nx[r][1] = 2.f * xo.y - ac[r][1];
                        nx[r][2] = 2.f * xo.z - ac[r][2];
                        nx[r][3] = 2.f * xo.w - ac[r][3];
                    }
                }
                __syncthreads();
                if (t < 256) {
                    #pragma unroll
                    for (int r = 0; r < 4; r++) {
                        *(float4*)&X[IDX(i0 + r, j0)] =
                            make_float4(nx[r][0], nx[r][1], nx[r][2], nx[r][3]);
                        #pragma unroll
                        for (int s = 0; s < 4; s++) Xt[IDX(j0 + s, i0 + r)] = nx[r][s];
                    }
                }
                __syncthreads();
            }
            if (t < 256) {
                #pragma unroll
                for (int r = 0; r < 4; r++)
                    *(float4*)&ws[OFF_VINV + (i0 + r) * DD + j0] =
                        make_float4(nx[r][0], nx[r][1], nx[r][2], nx[r][3]);
            }
            // EAT = (E@alpha)^T -> ws, staged into Vt / T (both dead)
            for (int idx = t; idx < KK * DD; idx += 512) {
                int k = idx >> 6, d = idx & 63;
                float ea = 0.f;
                #pragma unroll
                for (int r = 0; r < RR; r++)
                    ea = fmaf(E[d * RR + r], alpha[r * KK + k], ea);
                ws[OFF_EAT + idx] = ea;
                if (k < 64) Vt[k * 64 + d] = ea; else T[(k - 64) * 64 + d] = ea;
            }
            __syncthreads();
            // RHT[k][d] = sum_j Vinv[d][j] * EA[j][k];  Vinv[d][j] = Xt[IDX(j,d)]
            for (int idx = t; idx < KK * DD; idx += 512) {
                int k = idx >> 6, d = idx & 63;
                const float* ea = (k < 64) ? &Vt[k * 64] : &T[(k - 64) * 64];
                float rr = 0.f;
                for (int j = 0; j < DD; j++) rr = fmaf(Xt[IDX(j, d)], ea[j], rr);
                ws[OFF_RHT + idx] = rr;
            }
            if (t < DD) {   // y0 = Vinv @ x0
                float s = 0.f;
                for (int j = 0; j < DD; j++) s = fmaf(Xt[IDX(j, t)], x0[j], s);
                ws[OFF_Y0 + t] = s;
            }
            __syncthreads();   // Newton LDS dead; safe for GEMM reuse
        }
        // ---- GEMM: C[32 x 96] for segment b -> ws ----
        {
            float* uT = sm;            // 32x64 swizzled
            float* mT = sm + 2048;     // 96x64 swizzled
            const int n0 = b * SB;
            const int tn = t & 15, tm = t >> 4;
            float acc0 = 0.f, acc1 = 0.f, acc2 = 0.f,
                  acc3 = 0.f, acc4 = 0.f, acc5 = 0.f;
            for (int kc = 0; kc < HH; kc += 64) {
                {
                    int r = t >> 4, c4 = t & 15;
                    float4 f4 = *(const float4*)&u[(n0 + r) * HH + kc + c4 * 4];
                    *(float4*)&uT[r * 64 + ((c4 ^ (r & 7)) << 2)] = f4;
                }
                #pragma unroll
                for (int s2 = 0; s2 < 3; s2++) {
                    int idx = t + 512 * s2;
                    int r = idx >> 4, c4 = idx & 15;
                    const float* src = (r < 32) ? &gate_w[r * HH] : &B[(r - 32) * HH];
                    float4 f4 = *(const float4*)&src[kc + c4 * 4];
                    *(float4*)&mT[r * 64 + ((c4 ^ (r & 7)) << 2)] = f4;
                }
                __syncthreads();
                #pragma unroll
                for (int k4 = 0; k4 < 16; k4++) {
                    float4 uu[2], mm[3];
                    #pragma unroll
                    for (int i = 0; i < 2; i++) {
                        int rr = 2 * tn + i;
                        uu[i] = *(float4*)&uT[rr * 64 + ((k4 ^ (rr & 7)) << 2)];
                    }
                    #pragma unroll
                    for (int j = 0; j < 3; j++) {
                        int m = 3 * tm + j;
                        mm[j] = *(float4*)&mT[m * 64 + ((k4 ^ (m & 7)) << 2)];
                    }
                    acc0 += uu[0].x*mm[0].x + uu[0].y*mm[0].y + uu[0].z*mm[0].z + uu[0].w*mm[0].w;
                    acc1 += uu[0].x*mm[1].x + uu[0].y*mm[1].y + uu[0].z*mm[1].z + uu[0].w*mm[1].w;
                    acc2 += uu[0].x*mm[2].x + uu[0].y*mm[2].y + uu[0].z*mm[2].z + uu[0].w*mm[2].w;
                    acc3 += uu[1].x*mm[0].x + uu[1].y*mm[0].y + uu[1].z*mm[0].z + uu[1].w*mm[0].w;
                    acc4 += uu[1].x*mm[1].x + uu[1].y*mm[1].y + uu[1].z*mm[1].z + uu[1].w*mm[1].w;
                    acc5 += uu[1].x*mm[2].x + uu[1].y*mm[2].y + uu[1].z*mm[2].z + uu[1].w*mm[2].w;
                }
                __syncthreads();
            }
            float* Cw = ws + OFF_C + (size_t)b * SB * MM;
            Cw[(2*tn+0) * MM + 3*tm+0] = acc0;
            Cw[(2*tn+0) * MM + 3*tm+1] = acc1;
            Cw[(2*tn+0) * MM + 3*tm+2] = acc2;
            Cw[(2*tn+1) * MM + 3*tm+0] = acc3;
            Cw[(2*tn+1) * MM + 3*tm+1] = acc4;
            Cw[(2*tn+1) * MM + 3*tm+2] = acc5;
        }
    }
    if (phase == 7) { __threadfence(); grid.sync(); }

    // ================= P1: w-transform + coefficients + segment aggregate ===
    if (phase & 2) {
        const int n0 = b * SB;
        for (int idx = t; idx < DD * DD; idx += 512) {
            int d = idx >> 6, j = idx & 63;
            sm[j * 68 + d] = ws[OFF_VINV + idx];         // vinvT[j][d] = Vinv[d][j]
        }
        for (int idx = t; idx < SB * MM; idx += 512)
            sm[L1_CT + idx] = ws[OFF_C + (size_t)b * SB * MM + idx];
        __syncthreads();
        // w-transform in LDS: what[nl][d] = sum_j craw[nl][32+j] * Vinv[d][j]
        {
            const int nl = t >> 4, d0 = (t & 15) << 2;
            float4 a = {0.f, 0.f, 0.f, 0.f};
            for (int j = 0; j < DD; j++) {
                float cr = sm[L1_CT + nl * MM + 32 + j];
                float4 v4 = *(float4*)&sm[j * 68 + d0];
                a.x = fmaf(cr, v4.x, a.x); a.y = fmaf(cr, v4.y, a.y);
                a.z = fmaf(cr, v4.z, a.z); a.w = fmaf(cr, v4.w, a.w);
            }
            __syncthreads();
            *(float4*)&sm[L1_CT + nl * MM + 32 + d0] = a;
        }
        __syncthreads();
        // per-thread coefs: chunk c = t>>5 (2 steps), pole p = t&31
        const int c = t >> 5, p = t & 31;
        const float nlr = -sp_fast(llr[p]);
        const float imag = lim[p], gb = gate_b[p];
        float4 cfs[2];
        #pragma unroll
        for (int i = 0; i < 2; i++) {
            int nl = c * 2 + i, n = n0 + nl;
            float dtv = times[n] - (n ? times[n - 1] : 0.f);
            float gate = sp_fast(sm[L1_CT + nl * MM + p] + gb);
            float real = nlr * gate;
            float e = __expf(real * dtv);
            float x = imag * dtv, x2 = x * x;
            float cb = 1.f - x2 * (0.5f - x2 * (1.f / 24.f));
            float sb = x * (1.f - x2 * ((1.f / 6.f) - x2 * (1.f / 120.f)));
            float a = e * cb, cc = e * sb;
            float denom = real * real + imag * imag;
            float inv = rcp_fast(denom + 1e-12f);
            float nre = a - 1.f, nim = cc;
            float qr = (nre * real + nim * imag) * inv;
            float qi = (nim * real - nre * imag) * inv;
            if (denom < 1e-8f) { qr = dtv; qi = 0.f; }
            float2 w = *(float2*)&sm[L1_CT + nl * MM + 32 + 2 * p];
            float br = qr * w.x - qi * w.y;
            float bi = qr * w.y + qi * w.x;
            if (!(dtv > 0.f)) { br = 0.f; bi = 0.f; }
            int mk = marks[n];
            float2 rh = *(const float2*)&ws[OFF_RHT + mk * DD + 2 * p];
            cfs[i] = make_float4(a, cc, br + rh.x, bi + rh.y);
            *(float4*)&ws[OFF_COEF + ((size_t)n * PP + p) * 4] = cfs[i];
        }
        ((float4*)(sm + L1_AG))[c * 32 + p] = comp_aff(cfs[1], cfs[0]);
        __syncthreads();
        if (t < PP) {
            float4 T = make_float4(1.f, 0.f, 0.f, 0.f);
            #pragma unroll
            for (int cc = 0; cc < 16; cc++)
                T = comp_aff(((float4*)(sm + L1_AG))[cc * 32 + t], T);
            *(float4*)&ws[OFF_BAGG + (b * PP + t) * 4] = T;
        }
    }
    if (phase == 7) { __threadfence(); grid.sync(); }

    // ================= P2: prefix + replay + matvec + outputs ===============
    if (phase & 4) {
        const int n0 = b * SB;
        const int c = t >> 5, p = t & 31;
        for (int idx = t; idx < DD * DD; idx += 512) {
            int d = idx >> 6, k = idx & 63;
            sm[k * 68 + d] = V[idx];                     // vt[k][d] = V[d][k]
        }
        float4 cf0 = *(float4*)&ws[OFF_COEF + ((size_t)(n0 + c * 2)     * PP + p) * 4];
        float4 cf1 = *(float4*)&ws[OFF_COEF + ((size_t)(n0 + c * 2 + 1) * PP + p) * 4];
        float4* ag   = (float4*)(sm + L2_AG);
        float4* pref = (float4*)(sm + L2_PREF);
        float2* yb   = (float2*)(sm + L2_YB);
        ag[c * 32 + p] = comp_aff(cf1, cf0);
        {   // group prefix over BAGG[0..b): group c covers [16c, min(b,16c+16))
            int q0 = c * 16, q1 = min(b, q0 + 16);
            float4 Q = make_float4(1.f, 0.f, 0.f, 0.f);
            for (int q = q0; q < q1; q++)
                Q = comp_aff(*(const float4*)&ws[OFF_BAGG + (q * PP + p) * 4], Q);
            pref[c * 32 + p] = Q;
        }
        __syncthreads();
        if (t < PP) {
            float2 y = *(const float2*)&ws[OFF_Y0 + 2 * t];
            #pragma unroll
            for (int jg = 0; jg < 16; jg++) {
                float4 Q = pref[jg * 32 + t];
                float nyr = Q.x * y.x - Q.y * y.y + Q.z;
                float nyi = Q.x * y.y + Q.y * y.x + Q.w;
                y.x = nyr; y.y = nyi;
            }
            yb[t] = y;
        }
        __syncthreads();
        {   // replay: intra-segment prefix (chunk aggs), then 2 coefs
            float2 y = yb[p];
            #pragma unroll
            for (int cc = 0; cc < 15; cc++) {
                if (cc < c) {
                    float4 A = ag[cc * 32 + p];
                    float nyr = A.x * y.x - A.y * y.y + A.z;
                    float nyi = A.x * y.y + A.y * y.x + A.w;
                    y.x = nyr; y.y = nyi;
                }
            }
            float nyr = cf0.x * y.x - cf0.y * y.y + cf0.z;
            float nyi = cf0.x * y.y + cf0.y * y.x + cf0.w;
            y.x = nyr; y.y = nyi;
            *(float2*)&sm[L2_YL + (c * 2 + 0) * 68 + 2 * p] = y;
            nyr = cf1.x * y.x - cf1.y * y.y + cf1.z;
            nyi = cf1.x * y.y + cf1.y * y.x + cf1.w;
            y.x = nyr; y.y = nyi;
            *(float2*)&sm[L2_YL + (c * 2 + 1) * 68 + 2 * p] = y;
        }
        __syncthreads();
        {   // matvec: out[n] = V @ y[n]; x_left = out - EAT[:,mark]
            const int nr = t >> 4, d0 = (t & 15) << 2;
            float4 a = {0.f, 0.f, 0.f, 0.f};
            for (int k = 0; k < DD; k++) {
                float yv = sm[L2_YL + nr * 68 + k];
                float4 v4 = *(float4*)&sm[k * 68 + d0];
                a.x = fmaf(yv, v4.x, a.x); a.y = fmaf(yv, v4.y, a.y);
                a.z = fmaf(yv, v4.z, a.z); a.w = fmaf(yv, v4.w, a.w);
            }
            int n = n0 + nr;
            int mk = marks[n];
            *(float4*)&out[(size_t)n * DD + d0] = a;
            float4 e4 = *(const float4*)&ws[OFF_EAT + mk * DD + d0];
            a.x -= e4.x; a.y -= e4.y; a.z -= e4.z; a.w -= e4.w;
            *(float4*)&out[(size_t)NN * DD + (size_t)n * DD + d0] = a;
        }
    }
}

// ---------------------------------------------------------------------------
extern "C" void kernel_launch(void* const* d_in, const int* in_sizes, int n_in,
                              void* d_out, int out_size, void* d_ws, size_t ws_size,
                              hipStream_t stream) {
    (void)in_sizes; (void)n_in; (void)out_size; (void)ws_size;
    const float* times  = (const float*)d_in[0];
    const int*   marks  = (const int*)d_in[1];
    const float* u      = (const float*)d_in[2];
    const float* llr    = (const float*)d_in[3];
    const float* lim    = (const float*)d_in[4];
    const float* V      = (const float*)d_in[5];
    const float* B      = (const float*)d_in[6];
    const float* E      = (const float*)d_in[7];
    const float* alpha  = (const float*)d_in[8];
    const float* gate_w = (const float*)d_in[9];
    const float* gate_b = (const float*)d_in[10];
    const float* x0     = (const float*)d_in[11];
    float* ws  = (float*)d_ws;
    float* out = (float*)d_out;

    int phase = 7;
    void* args[] = { (void*)&times, (void*)&marks, (void*)&u, (void*)&llr,
                     (void*)&lim, (void*)&V, (void*)&B, (void*)&E,
                     (void*)&alpha, (void*)&gate_w, (void*)&gate_b, (void*)&x0,
                     (void*)&ws, (void*)&out, (void*)&phase };
    hipError_t err = hipLaunchCooperativeKernel(
        reinterpret_cast<void*>(mega), dim3(NSEG), dim3(512), args, 0, stream);
    if (err != hipSuccess) {
        (void)hipGetLastError();   // clear sticky error, take 3-launch path
        hipLaunchKernelGGL(mega, dim3(NSEG), dim3(512), 0, stream,
                           times, marks, u, llr, lim, V, B, E, alpha,
                           gate_w, gate_b, x0, ws, out, 1);
        hipLaunchKernelGGL(mega, dim3(NSEG), dim3(512), 0, stream,
                           times, marks, u, llr, lim, V, B, E, alpha,
                           gate_w, gate_b, x0, ws, out, 2);
        hipLaunchKernelGGL(mega, dim3(NSEG), dim3(512), 0, stream,
                           times, marks, u, llr, lim, V, B, E, alpha,
                           gate_w, gate_b, x0, ws, out, 4);
    }
}

// Round 7
// 164.583 us; speedup vs baseline: 1.9919x; 1.9919x over previous
//
#include <hip/hip_runtime.h>
#include <math.h>

#define NN 8192
#define PP 32
#define HH 512
#define KK 100
#define DD 64
#define RR 32
#define MM 96            // C cols: 32 gate + 64 w
#define SB 32            // steps per segment
#define NSEG 256         // segments

// workspace layout (float offsets)
#define OFF_VINV 0            // 64*64
#define OFF_EAT  4096         // 100*64 (E@alpha)^T
#define OFF_RHT  10496        // 100*64 (Vinv@E@alpha)^T
#define OFF_Y0   16896        // 64
#define OFF_BAGG 16960        // 256*32*4 segment aggregates
#define OFF_C    49728        // 8192*96 gemm out
#define OFF_COEF 836160       // 8192*32*4 step coefficients

__device__ __forceinline__ float sp_fast(float x) {   // softplus
    return x > 15.f ? x : __logf(1.f + __expf(x));
}
__device__ __forceinline__ float rcp_fast(float x) {
    float r;
    asm("v_rcp_f32 %0, %1" : "=v"(r) : "v"(x));
    return r;
}
__device__ __forceinline__ float4 comp_aff(float4 f, float4 g) {  // f after g
    float4 r;
    r.x = f.x * g.x - f.y * g.y;
    r.y = f.x * g.y + f.y * g.x;
    r.z = f.x * g.z - f.y * g.w + f.z;
    r.w = f.x * g.w + f.y * g.z + f.w;
    return r;
}

#define IDX(r,c) ((r)*64 + ((c) ^ (((r)&7)<<2)))

// ===========================================================================
// g0: blocks 0..255 GEMM (C = u @ [gate_w; B]^T, 32 rows each);
//     block 256: Newton inverse (2 iters) + EAT + RHT + y0.
__global__ void __launch_bounds__(512) g0(
    const float* __restrict__ u, const float* __restrict__ gate_w,
    const float* __restrict__ B, const float* __restrict__ V,
    const float* __restrict__ E, const float* __restrict__ alpha,
    const float* __restrict__ x0, float* __restrict__ ws) {
    __shared__ float sm[16384];
    const int b = blockIdx.x, t = threadIdx.x;

    if (b == NSEG) {
        // ---- Newton inverse: X0 = 2I - V; 2x X <- X(2I - V X) ----
        float* Vt = sm;            // Vt[k][i] = V[i][k] (swizzled)
        float* X  = sm + 4096;
        float* Xt = sm + 8192;     // Xt[k][i] = X[i][k]
        float* T  = sm + 12288;
        const int i0 = (t >> 4) << 1;    // 2 rows
        const int j0 = (t & 15) << 2;    // 4 cols
        float nx[2][4];
        #pragma unroll
        for (int r = 0; r < 2; r++) {
            float4 v4 = *(const float4*)&V[(i0 + r) * DD + j0];
            float vv[4] = {v4.x, v4.y, v4.z, v4.w};
            #pragma unroll
            for (int s = 0; s < 4; s++) {
                Vt[IDX(j0 + s, i0 + r)] = vv[s];
                float xv = ((i0 + r) == (j0 + s) ? 2.f : 0.f) - vv[s];
                nx[r][s] = xv;
                Xt[IDX(j0 + s, i0 + r)] = xv;
            }
            *(float4*)&X[IDX(i0 + r, j0)] =
                make_float4(nx[r][0], nx[r][1], nx[r][2], nx[r][3]);
        }
        __syncthreads();
        for (int it = 0; it < 2; it++) {
            float ac[2][4];
            #pragma unroll
            for (int r = 0; r < 2; r++)
                #pragma unroll
                for (int s = 0; s < 4; s++) ac[r][s] = 0.f;
            for (int k = 0; k < DD; k++) {          // T = V @ X
                float2 a2 = *(float2*)&Vt[IDX(k, i0)];
                float4 b4 = *(float4*)&X[IDX(k, j0)];
                float bv[4] = {b4.x, b4.y, b4.z, b4.w};
                #pragma unroll
                for (int s = 0; s < 4; s++) {
                    ac[0][s] = fmaf(a2.x, bv[s], ac[0][s]);
                    ac[1][s] = fmaf(a2.y, bv[s], ac[1][s]);
                }
            }
            #pragma unroll
            for (int r = 0; r < 2; r++)
                *(float4*)&T[IDX(i0 + r, j0)] =
                    make_float4(ac[r][0], ac[r][1], ac[r][2], ac[r][3]);
            __syncthreads();
            #pragma unroll
            for (int r = 0; r < 2; r++)
                #pragma unroll
                for (int s = 0; s < 4; s++) ac[r][s] = 0.f;
            for (int k = 0; k < DD; k++) {          // X @ T
                float2 a2 = *(float2*)&Xt[IDX(k, i0)];
                float4 b4 = *(float4*)&T[IDX(k, j0)];
                float bv[4] = {b4.x, b4.y, b4.z, b4.w};
                #pragma unroll
                for (int s = 0; s < 4; s++) {
                    ac[0][s] = fmaf(a2.x, bv[s], ac[0][s]);
                    ac[1][s] = fmaf(a2.y, bv[s], ac[1][s]);
                }
            }
            #pragma unroll
            for (int r = 0; r < 2; r++) {
                float4 xo = *(float4*)&X[IDX(i0 + r, j0)];
                nx[r][0] = 2.f * xo.x - ac[r][0];
                nx[r][1] = 2.f * xo.y - ac[r][1];
                nx[r][2] = 2.f * xo.z - ac[r][2];
                nx[r][3] = 2.f * xo.w - ac[r][3];
            }
            __syncthreads();
            #pragma unroll
            for (int r = 0; r < 2; r++) {
                *(float4*)&X[IDX(i0 + r, j0)] =
                    make_float4(nx[r][0], nx[r][1], nx[r][2], nx[r][3]);
                #pragma unroll
                for (int s = 0; s < 4; s++) Xt[IDX(j0 + s, i0 + r)] = nx[r][s];
            }
            __syncthreads();
        }
        #pragma unroll
        for (int r = 0; r < 2; r++)
            *(float4*)&ws[OFF_VINV + (i0 + r) * DD + j0] =
                make_float4(nx[r][0], nx[r][1], nx[r][2], nx[r][3]);
        // ---- EAT = (E@alpha)^T -> ws, staged into Vt / T (dead) ----
        for (int idx = t; idx < KK * DD; idx += 512) {
            int k = idx >> 6, d = idx & 63;
            float ea = 0.f;
            #pragma unroll
            for (int r = 0; r < RR; r++)
                ea = fmaf(E[d * RR + r], alpha[r * KK + k], ea);
            ws[OFF_EAT + idx] = ea;
            if (k < 64) Vt[k * 64 + d] = ea; else T[(k - 64) * 64 + d] = ea;
        }
        __syncthreads();
        // ---- RHT[k][d] = sum_j Vinv[d][j]*EA[j][k];  Vinv[d][j] = Xt[IDX(j,d)]
        for (int idx = t; idx < KK * DD; idx += 512) {
            int k = idx >> 6, d = idx & 63;
            const float* ea = (k < 64) ? &Vt[k * 64] : &T[(k - 64) * 64];
            float rr = 0.f;
            for (int j = 0; j < DD; j++) rr = fmaf(Xt[IDX(j, d)], ea[j], rr);
            ws[OFF_RHT + idx] = rr;
        }
        if (t < DD) {   // y0 = Vinv @ x0
            float s = 0.f;
            for (int j = 0; j < DD; j++) s = fmaf(Xt[IDX(j, t)], x0[j], s);
            ws[OFF_Y0 + t] = s;
        }
        return;
    }

    // ---- GEMM: C[32 x 96] for segment b ----
    float* uT = sm;            // 32x64 swizzled
    float* mT = sm + 2048;     // 96x64 swizzled
    const int n0 = b * SB;
    const int tn = t & 15, tm = t >> 4;
    float acc0 = 0.f, acc1 = 0.f, acc2 = 0.f, acc3 = 0.f, acc4 = 0.f, acc5 = 0.f;
    for (int kc = 0; kc < HH; kc += 64) {
        {
            int r = t >> 4, c4 = t & 15;
            float4 f4 = *(const float4*)&u[(n0 + r) * HH + kc + c4 * 4];
            *(float4*)&uT[r * 64 + ((c4 ^ (r & 7)) << 2)] = f4;
        }
        #pragma unroll
        for (int s2 = 0; s2 < 3; s2++) {
            int idx = t + 512 * s2;
            int r = idx >> 4, c4 = idx & 15;
            const float* src = (r < 32) ? &gate_w[r * HH] : &B[(r - 32) * HH];
            float4 f4 = *(const float4*)&src[kc + c4 * 4];
            *(float4*)&mT[r * 64 + ((c4 ^ (r & 7)) << 2)] = f4;
        }
        __syncthreads();
        #pragma unroll
        for (int k4 = 0; k4 < 16; k4++) {
            float4 uu[2], mm[3];
            #pragma unroll
            for (int i = 0; i < 2; i++) {
                int rr = 2 * tn + i;
                uu[i] = *(float4*)&uT[rr * 64 + ((k4 ^ (rr & 7)) << 2)];
            }
            #pragma unroll
            for (int j = 0; j < 3; j++) {
                int m = 3 * tm + j;
                mm[j] = *(float4*)&mT[m * 64 + ((k4 ^ (m & 7)) << 2)];
            }
            acc0 += uu[0].x*mm[0].x + uu[0].y*mm[0].y + uu[0].z*mm[0].z + uu[0].w*mm[0].w;
            acc1 += uu[0].x*mm[1].x + uu[0].y*mm[1].y + uu[0].z*mm[1].z + uu[0].w*mm[1].w;
            acc2 += uu[0].x*mm[2].x + uu[0].y*mm[2].y + uu[0].z*mm[2].z + uu[0].w*mm[2].w;
            acc3 += uu[1].x*mm[0].x + uu[1].y*mm[0].y + uu[1].z*mm[0].z + uu[1].w*mm[0].w;
            acc4 += uu[1].x*mm[1].x + uu[1].y*mm[1].y + uu[1].z*mm[1].z + uu[1].w*mm[1].w;
            acc5 += uu[1].x*mm[2].x + uu[1].y*mm[2].y + uu[1].z*mm[2].z + uu[1].w*mm[2].w;
        }
        __syncthreads();
    }
    float* Cw = ws + OFF_C + (size_t)b * SB * MM;
    Cw[(2*tn+0) * MM + 3*tm+0] = acc0;
    Cw[(2*tn+0) * MM + 3*tm+1] = acc1;
    Cw[(2*tn+0) * MM + 3*tm+2] = acc2;
    Cw[(2*tn+1) * MM + 3*tm+0] = acc3;
    Cw[(2*tn+1) * MM + 3*tm+1] = acc4;
    Cw[(2*tn+1) * MM + 3*tm+2] = acc5;
}

// ===========================================================================
// g1: per segment: w-transform (Vinv) + step coefficients -> COEF + BAGG.
// LDS: vinvT[j*68+d] @0 (4352), CT 32x100 @4352 (3200), AG f4[16][32] @7552
__global__ void __launch_bounds__(512) g1(
    const float* __restrict__ times, const int* __restrict__ marks,
    const float* __restrict__ llr, const float* __restrict__ lim,
    const float* __restrict__ gate_b, float* __restrict__ ws) {
    __shared__ float sm[9600];
    const int b = blockIdx.x, t = threadIdx.x;
    const int n0 = b * SB;
    for (int idx = t; idx < DD * DD; idx += 512) {
        int d = idx >> 6, j = idx & 63;
        sm[j * 68 + d] = ws[OFF_VINV + idx];      // vinvT[j][d] = Vinv[d][j]
    }
    {   // C tile -> LDS, stride 100 (bank-conflict-free nl groups)
        int r = t >> 4, c0 = (t & 15) * 6;
        const float* Cg = ws + OFF_C + (size_t)b * SB * MM + r * MM + c0;
        float* Cl = sm + 4352 + r * 100 + c0;
        #pragma unroll
        for (int q = 0; q < 3; q++)
            *(float2*)&Cl[2 * q] = *(const float2*)&Cg[2 * q];
    }
    __syncthreads();
    {   // w-transform: what[nl][d] = sum_j craw[nl][32+j] * Vinv[d][j]
        const int nl = t >> 4, d0 = (t & 15) << 2;
        float4 a = {0.f, 0.f, 0.f, 0.f};
        for (int j = 0; j < DD; j++) {
            float cr = sm[4352 + nl * 100 + 32 + j];
            float4 v4 = *(float4*)&sm[j * 68 + d0];
            a.x = fmaf(cr, v4.x, a.x); a.y = fmaf(cr, v4.y, a.y);
            a.z = fmaf(cr, v4.z, a.z); a.w = fmaf(cr, v4.w, a.w);
        }
        __syncthreads();
        *(float4*)&sm[4352 + nl * 100 + 32 + d0] = a;
    }
    __syncthreads();
    // per-thread coefs: chunk c = t>>5 (2 steps), pole p = t&31
    const int c = t >> 5, p = t & 31;
    const float nlr = -sp_fast(llr[p]);
    const float imag = lim[p], gb = gate_b[p];
    float4 cfs[2];
    #pragma unroll
    for (int i = 0; i < 2; i++) {
        int nl = c * 2 + i, n = n0 + nl;
        float dtv = times[n] - (n ? times[n - 1] : 0.f);
        float gate = sp_fast(sm[4352 + nl * 100 + p] + gb);
        float real = nlr * gate;
        float e = __expf(real * dtv);
        float x = imag * dtv, x2 = x * x;
        float cb = 1.f - x2 * (0.5f - x2 * (1.f / 24.f));
        float sb = x * (1.f - x2 * ((1.f / 6.f) - x2 * (1.f / 120.f)));
        float a = e * cb, cc = e * sb;
        float denom = real * real + imag * imag;
        float inv = rcp_fast(denom + 1e-12f);
        float nre = a - 1.f, nim = cc;
        float qr = (nre * real + nim * imag) * inv;
        float qi = (nim * real - nre * imag) * inv;
        if (denom < 1e-8f) { qr = dtv; qi = 0.f; }
        float2 w = *(float2*)&sm[4352 + nl * 100 + 32 + 2 * p];
        float br = qr * w.x - qi * w.y;
        float bi = qr * w.y + qi * w.x;
        if (!(dtv > 0.f)) { br = 0.f; bi = 0.f; }
        int mk = marks[n];
        float2 rh = *(const float2*)&ws[OFF_RHT + mk * DD + 2 * p];
        cfs[i] = make_float4(a, cc, br + rh.x, bi + rh.y);
        *(float4*)&ws[OFF_COEF + ((size_t)n * PP + p) * 4] = cfs[i];
    }
    float4* ag = (float4*)(sm + 7552);
    ag[c * 32 + p] = comp_aff(cfs[1], cfs[0]);
    __syncthreads();
    if (t < PP) {
        float4 T = make_float4(1.f, 0.f, 0.f, 0.f);
        #pragma unroll
        for (int cc = 0; cc < 16; cc++) T = comp_aff(ag[cc * 32 + t], T);
        *(float4*)&ws[OFF_BAGG + (b * PP + t) * 4] = T;
    }
}

// ===========================================================================
// g2: prefix over BAGG + replay + matvec + outputs.
// LDS: vt[k*68+d] @0 (4352), AG f4 @4352 (2048), PREF f4 @6400 (2048),
//      YL 32x68 @8448 (2176), YB @10624 (64)
__global__ void __launch_bounds__(512) g2(
    const float* __restrict__ V, const int* __restrict__ marks,
    const float* __restrict__ ws, float* __restrict__ out) {
    __shared__ float sm[10688];
    const int b = blockIdx.x, t = threadIdx.x;
    const int n0 = b * SB;
    const int c = t >> 5, p = t & 31;
    for (int idx = t; idx < DD * DD; idx += 512) {
        int d = idx >> 6, k = idx & 63;
        sm[k * 68 + d] = V[idx];                  // vt[k][d] = V[d][k]
    }
    float4 cf0 = *(const float4*)&ws[OFF_COEF + ((size_t)(n0 + c * 2)     * PP + p) * 4];
    float4 cf1 = *(const float4*)&ws[OFF_COEF + ((size_t)(n0 + c * 2 + 1) * PP + p) * 4];
    float4* ag   = (float4*)(sm + 4352);
    float4* pref = (float4*)(sm + 6400);
    float2* yb   = (float2*)(sm + 10624);
    ag[c * 32 + p] = comp_aff(cf1, cf0);
    {   // group prefix over BAGG[0..b): group c covers [16c, min(b,16c+16))
        int q0 = c * 16, q1 = min(b, q0 + 16);
        float4 Q = make_float4(1.f, 0.f, 0.f, 0.f);
        for (int q = q0; q < q1; q++)
            Q = comp_aff(*(const float4*)&ws[OFF_BAGG + (q * PP + p) * 4], Q);
        pref[c * 32 + p] = Q;
    }
    __syncthreads();
    if (t < PP) {
        float2 y = *(const float2*)&ws[OFF_Y0 + 2 * t];
        #pragma unroll
        for (int jg = 0; jg < 16; jg++) {
            float4 Q = pref[jg * 32 + t];
            float nyr = Q.x * y.x - Q.y * y.y + Q.z;
            float nyi = Q.x * y.y + Q.y * y.x + Q.w;
            y.x = nyr; y.y = nyi;
        }
        yb[t] = y;
    }
    __syncthreads();
    {   // replay: intra-segment prefix (chunk aggs), then 2 coefs
        float2 y = yb[p];
        #pragma unroll
        for (int cc = 0; cc < 15; cc++) {
            if (cc < c) {
                float4 A = ag[cc * 32 + p];
                float nyr = A.x * y.x - A.y * y.y + A.z;
                float nyi = A.x * y.y + A.y * y.x + A.w;
                y.x = nyr; y.y = nyi;
            }
        }
        float nyr = cf0.x * y.x - cf0.y * y.y + cf0.z;
        float nyi = cf0.x * y.y + cf0.y * y.x + cf0.w;
        y.x = nyr; y.y = nyi;
        *(float2*)&sm[8448 + (c * 2 + 0) * 68 + 2 * p] = y;
        nyr = cf1.x * y.x - cf1.y * y.y + cf1.z;
        nyi = cf1.x * y.y + cf1.y * y.x + cf1.w;
        y.x = nyr; y.y = nyi;
        *(float2*)&sm[8448 + (c * 2 + 1) * 68 + 2 * p] = y;
    }
    __syncthreads();
    {   // matvec: out[n] = V @ y[n]; x_left = out - EAT[:,mark]
        const int nr = t >> 4, d0 = (t & 15) << 2;
        float4 a = {0.f, 0.f, 0.f, 0.f};
        for (int k = 0; k < DD; k++) {
            float yv = sm[8448 + nr * 68 + k];
            float4 v4 = *(float4*)&sm[k * 68 + d0];
            a.x = fmaf(yv, v4.x, a.x); a.y = fmaf(yv, v4.y, a.y);
            a.z = fmaf(yv, v4.z, a.z); a.w = fmaf(yv, v4.w, a.w);
        }
        int n = n0 + nr;
        int mk = marks[n];
        *(float4*)&out[(size_t)n * DD + d0] = a;
        float4 e4 = *(const float4*)&ws[OFF_EAT + mk * DD + d0];
        a.x -= e4.x; a.y -= e4.y; a.z -= e4.z; a.w -= e4.w;
        *(float4*)&out[(size_t)NN * DD + (size_t)n * DD + d0] = a;
    }
}

// ---------------------------------------------------------------------------
extern "C" void kernel_launch(void* const* d_in, const int* in_sizes, int n_in,
                              void* d_out, int out_size, void* d_ws, size_t ws_size,
                              hipStream_t stream) {
    (void)in_sizes; (void)n_in; (void)out_size; (void)ws_size;
    const float* times  = (const float*)d_in[0];
    const int*   marks  = (const int*)d_in[1];
    const float* u      = (const float*)d_in[2];
    const float* llr    = (const float*)d_in[3];
    const float* lim    = (const float*)d_in[4];
    const float* V      = (const float*)d_in[5];
    const float* B      = (const float*)d_in[6];
    const float* E      = (const float*)d_in[7];
    const float* alpha  = (const float*)d_in[8];
    const float* gate_w = (const float*)d_in[9];
    const float* gate_b = (const float*)d_in[10];
    const float* x0     = (const float*)d_in[11];
    float* ws  = (float*)d_ws;
    float* out = (float*)d_out;

    hipLaunchKernelGGL(g0, dim3(NSEG + 1), dim3(512), 0, stream,
                       u, gate_w, B, V, E, alpha, x0, ws);
    hipLaunchKernelGGL(g1, dim3(NSEG), dim3(512), 0, stream,
                       times, marks, llr, lim, gate_b, ws);
    hipLaunchKernelGGL(g2, dim3(NSEG), dim3(512), 0, stream,
                       V, marks, ws, out);
}